// Round 3
// baseline (278.965 us; speedup 1.0000x reference)
//
#include <hip/hip_runtime.h>

#define IMAGE 224
#define PAD   30
#define CROP  164   // IMAGE - 2*PAD
#define BATCH 16
#define TT    16
#define W4    56    // IMAGE/4
#define PLANE4 (IMAGE * W4)          // float4s per (h,w) plane = 12544
#define PROMPT_F4 (BATCH * 3 * PLANE4)   // 602,112 float4s = 9.63 MB

typedef float v4f __attribute__((ext_vector_type(4)));

// ---------------- Pass 1: build prompt[b,c,h,w] into workspace ----------------
__global__ __launch_bounds__(256) void build_prompt_kernel(
    const float* __restrict__ pu1,  const float* __restrict__ pu10,
    const float* __restrict__ pd1,  const float* __restrict__ pd10,
    const float* __restrict__ pl1,  const float* __restrict__ pl10,
    const float* __restrict__ pr1,  const float* __restrict__ pr10,
    const int* __restrict__ cam_idx,
    const int* __restrict__ off_right,
    const int* __restrict__ off_down,
    float* __restrict__ prompt)
{
    const int idx = blockIdx.x * blockDim.x + threadIdx.x;
    if (idx >= PROMPT_F4) return;

    const int w4 = idx % W4;
    const int h  = (idx / W4) % IMAGE;
    const int c  = (idx / PLANE4) % 3;
    const int b  =  idx / (PLANE4 * 3);

    const int ci    = cam_idx[b];
    const int orr   = off_right[b];
    const int od    = off_down[b];
    const int off_l = 2 * PAD - orr;
    const int off_u = 2 * PAD - od;
    const int n10_l = off_l / 10;
    const int n10_u = off_u / 10;
    const int n1_r  = orr % 10;
    const int n1_d  = od % 10;

    const int w0      = w4 * 4;
    const int base_cc = ci * 3 + c;   // camera*3 + channel

    float p[4];

    if (h < off_u) {
        // --- top band: row taken from pad_up_{10,1} ---
        const float* rowp = (h < n10_u * 10)
            ? (pu10 + (size_t)(base_cc * 10 + (h % 10)) * IMAGE)
            : (pu1  + (size_t)base_cc * IMAGE);
        #pragma unroll
        for (int j = 0; j < 4; ++j) p[j] = rowp[w0 + j];
    } else if (h >= IMAGE - od) {
        // --- bottom band: row from pad_down_{1,10} ---
        const int hd = h - (IMAGE - od);          // >= 0
        const float* rowp = (hd < n1_d)
            ? (pd1  + (size_t)base_cc * IMAGE)
            : (pd10 + (size_t)(base_cc * 10 + ((hd - n1_d) % 10)) * IMAGE);
        #pragma unroll
        for (int j = 0; j < 4; ++j) p[j] = rowp[w0 + j];
    } else {
        // --- middle band: left / zero / right per-w ---
        int r = h - off_u;
        r = r < 0 ? 0 : (r > CROP - 1 ? CROP - 1 : r);
        #pragma unroll
        for (int j = 0; j < 4; ++j) {
            const int w = w0 + j;
            float v;
            if (w < off_l) {
                v = (w < n10_l * 10)
                    ? pl10[((size_t)base_cc * CROP + r) * 10 + (w % 10)]
                    : pl1 [ (size_t)base_cc * CROP + r];
            } else if (w >= IMAGE - orr) {
                const int wd = w - (IMAGE - orr);  // >= 0
                v = (wd < n1_r)
                    ? pr1 [ (size_t)base_cc * CROP + r]
                    : pr10[((size_t)base_cc * CROP + r) * 10 + ((wd - n1_r) % 10)];
            } else {
                v = 0.0f;
            }
            p[j] = v;
        }
    }

    v4f pv = { p[0], p[1], p[2], p[3] };
    *reinterpret_cast<v4f*>(prompt + (size_t)idx * 4) = pv;
}

// ---------------- Pass 2: out = x + prompt (broadcast over T) ----------------
// Memcpy-class streaming kernel: 2 independent float4s per thread, no
// divergence, prompt loads hit L2/L3 (9.6 MB table), nontemporal stores
// keep `out` from polluting L2.
__global__ __launch_bounds__(256) void add_prompt_kernel(
    const float* __restrict__ x,
    const float* __restrict__ prompt,
    float* __restrict__ out)
{
    const int i0 = blockIdx.x * 512 + threadIdx.x;   // float4 index, elem 0
    const int i1 = i0 + 256;                          // float4 index, elem 1
    // exact grid: 18816 blocks * 512 f4 == 9,633,792 == total; no bounds check

    // prompt f4 index: drop the t dimension.
    // flat f4 layout: ((b*3+c)*TT + t)*PLANE4 + (h*W4 + w4)
    const int bc0   = i0 / (PLANE4 * TT);
    const int rem0  = i0 % PLANE4;
    const int bc1   = i1 / (PLANE4 * TT);
    const int rem1  = i1 % PLANE4;

    const v4f xv0 = __builtin_nontemporal_load(
        reinterpret_cast<const v4f*>(x + (size_t)i0 * 4));
    const v4f xv1 = __builtin_nontemporal_load(
        reinterpret_cast<const v4f*>(x + (size_t)i1 * 4));
    const v4f pv0 = *reinterpret_cast<const v4f*>(
        prompt + ((size_t)bc0 * PLANE4 + rem0) * 4);
    const v4f pv1 = *reinterpret_cast<const v4f*>(
        prompt + ((size_t)bc1 * PLANE4 + rem1) * 4);

    __builtin_nontemporal_store(xv0 + pv0,
        reinterpret_cast<v4f*>(out + (size_t)i0 * 4));
    __builtin_nontemporal_store(xv1 + pv1,
        reinterpret_cast<v4f*>(out + (size_t)i1 * 4));
}

extern "C" void kernel_launch(void* const* d_in, const int* in_sizes, int n_in,
                              void* d_out, int out_size, void* d_ws, size_t ws_size,
                              hipStream_t stream) {
    const float* x    = (const float*)d_in[0];
    const float* pu1  = (const float*)d_in[1];
    const float* pu10 = (const float*)d_in[2];
    const float* pd1  = (const float*)d_in[3];
    const float* pd10 = (const float*)d_in[4];
    const float* pl1  = (const float*)d_in[5];
    const float* pl10 = (const float*)d_in[6];
    const float* pr1  = (const float*)d_in[7];
    const float* pr10 = (const float*)d_in[8];
    const int* cam_idx   = (const int*)d_in[9];
    const int* off_right = (const int*)d_in[10];
    const int* off_down  = (const int*)d_in[11];
    float* out    = (float*)d_out;
    float* prompt = (float*)d_ws;   // 9.63 MB scratch

    // Pass 1: 602,112 float4s -> 2352 blocks
    build_prompt_kernel<<<(PROMPT_F4 + 255) / 256, 256, 0, stream>>>(
        pu1, pu10, pd1, pd10, pl1, pl10, pr1, pr10,
        cam_idx, off_right, off_down, prompt);

    // Pass 2: 9,633,792 float4s, 2 per thread -> 18,816 blocks (exact)
    const int total_f4 = BATCH * 3 * TT * PLANE4;
    const int grid2 = total_f4 / 512;
    add_prompt_kernel<<<grid2, 256, 0, stream>>>(x, prompt, out);
}